// Round 12
// baseline (205.279 us; speedup 1.0000x reference)
//
#include <hip/hip_runtime.h>
#include <hip/hip_bf16.h>

typedef __hip_bfloat16 bf16;
typedef __attribute__((ext_vector_type(8))) short short8;
typedef __attribute__((ext_vector_type(4))) float f32x4;

static constexpr int NPOS = 65536;  // 64*64*16

__device__ __forceinline__ float bs2f(short s) {
  union { float f; unsigned u; } cv;
  cv.u = ((unsigned)(unsigned short)s) << 16;
  return cv.f;
}
__device__ __forceinline__ short f2bs(float f) {
  bf16 b = __float2bfloat16(f);
  short r;
  __builtin_memcpy(&r, &b, 2);
  return r;
}

// K1a: partial sums + xu materialization (bf16). 2048 blocks.
// z-interp indices/weights forced constexpr (no dynamic private-array index).
__global__ __launch_bounds__(256) void k_partial(const float* __restrict__ x,
                                                 const float* __restrict__ skip,
                                                 bf16* __restrict__ xu,
                                                 float* __restrict__ partials) {
  __shared__ float s1[256];
  __shared__ float s2[256];
  int b = blockIdx.x, tid = threadIdx.x;
  float sum = 0.f, sq = 0.f;
  if (b < 1024) {
    int c = b >> 4;
    int h = (b & 15) * 4 + (tid >> 6);
    int w = tid & 63;
    float fh = (float)h * (31.0f / 63.0f);
    int ih = (int)fh; if (ih > 30) ih = 30;
    float wh = fh - (float)ih;
    float fw = (float)w * (31.0f / 63.0f);
    int iw = (int)fw; if (iw > 30) iw = 30;
    float ww = fw - (float)iw;
    const float* base = x + c * 8192 + ih * 256 + iw * 8;
    float4 A0 = *(const float4*)(base);
    float4 A1 = *(const float4*)(base + 4);
    float4 B0 = *(const float4*)(base + 8);
    float4 B1 = *(const float4*)(base + 12);
    float4 C0 = *(const float4*)(base + 256);
    float4 C1 = *(const float4*)(base + 260);
    float4 D0 = *(const float4*)(base + 264);
    float4 D1 = *(const float4*)(base + 268);
    float ra[8] = {A0.x, A0.y, A0.z, A0.w, A1.x, A1.y, A1.z, A1.w};
    float rb[8] = {B0.x, B0.y, B0.z, B0.w, B1.x, B1.y, B1.z, B1.w};
    float rc[8] = {C0.x, C0.y, C0.z, C0.w, C1.x, C1.y, C1.z, C1.w};
    float rd[8] = {D0.x, D0.y, D0.z, D0.w, D1.x, D1.y, D1.z, D1.w};
    short8 o0, o1;
#define ZSTEP(zz)                                                              \
  {                                                                            \
    constexpr float fz = (float)(zz) * (7.0f / 15.0f);                         \
    constexpr int izr = (int)fz;                                               \
    constexpr int iz = (izr > 6) ? 6 : izr;                                    \
    constexpr float wz = fz - (float)iz;                                       \
    float va = ra[iz] * (1.f - wz) + ra[iz + 1] * wz;                          \
    float vb = rb[iz] * (1.f - wz) + rb[iz + 1] * wz;                          \
    float vc = rc[iz] * (1.f - wz) + rc[iz + 1] * wz;                          \
    float vd = rd[iz] * (1.f - wz) + rd[iz + 1] * wz;                          \
    float v0 = va * (1.f - ww) + vb * ww;                                      \
    float v1 = vc * (1.f - ww) + vd * ww;                                      \
    float v = v0 * (1.f - wh) + v1 * wh;                                       \
    sum += v; sq += v * v;                                                     \
    if ((zz) < 8) o0[(zz) & 7] = f2bs(v); else o1[(zz) & 7] = f2bs(v);         \
  }
    ZSTEP(0) ZSTEP(1) ZSTEP(2) ZSTEP(3) ZSTEP(4) ZSTEP(5) ZSTEP(6) ZSTEP(7)
    ZSTEP(8) ZSTEP(9) ZSTEP(10) ZSTEP(11) ZSTEP(12) ZSTEP(13) ZSTEP(14) ZSTEP(15)
#undef ZSTEP
    bf16* xo = xu + (size_t)c * NPOS + h * 1024 + w * 16;
    *(short8*)xo = o0;
    *(short8*)(xo + 8) = o1;
  } else {
    int bb = b - 1024;
    const float4* p =
        (const float4*)(skip + (size_t)(bb >> 4) * NPOS + (bb & 15) * 4096);
    for (int i = tid; i < 1024; i += 256) {
      float4 v = p[i];
      sum += v.x + v.y + v.z + v.w;
      sq += v.x * v.x + v.y * v.y + v.z * v.z + v.w * v.w;
    }
  }
  s1[tid] = sum; s2[tid] = sq;
  __syncthreads();
  for (int s = 128; s > 0; s >>= 1) {
    if (tid < s) { s1[tid] += s1[tid + s]; s2[tid] += s2[tid + s]; }
    __syncthreads();
  }
  if (tid == 0) { partials[2 * b] = s1[0]; partials[2 * b + 1] = s2[0]; }
}

// K2: MFMA projection (unchanged from R11).
__global__ __launch_bounds__(256) void k_proj_mfma(
    const bf16* __restrict__ xu, const float* __restrict__ skip,
    const float* __restrict__ partials,
    const float* __restrict__ Wk, const float* __restrict__ bk,
    const float* __restrict__ Wv, const float* __restrict__ bv,
    const float* __restrict__ Wq, const float* __restrict__ bq,
    bf16* __restrict__ kbuf, bf16* __restrict__ vbuf, bf16* __restrict__ qbuf) {
  __shared__ float stl[256];
  __shared__ short xa[64 * 72];
  __shared__ short wb[64 * 72];
  __shared__ short ob[64 * 72];
  int tid = threadIdx.x;
  int p0 = blockIdx.x * 64;

  if (tid < 128) {
    int isk = tid >> 6, c = tid & 63;
    int base = isk ? (1024 + c * 16) : (c * 16);
    float sum = 0.f, sq = 0.f;
#pragma unroll
    for (int j = 0; j < 16; j++) {
      sum += partials[2 * (base + j)];
      sq  += partials[2 * (base + j) + 1];
    }
    float m = sum * (1.0f / NPOS);
    float var = sq * (1.0f / NPOS) - m * m;
    stl[isk * 128 + c] = m;
    stl[isk * 128 + 64 + c] = rsqrtf(var + 1e-5f);
  }
  __syncthreads();

  for (int ii = tid; ii < 512; ii += 256) {
    int c = ii >> 3, t0 = (ii & 7) * 8;
    short8 v8 = *(const short8*)(xu + (size_t)c * NPOS + p0 + t0);
    float m = stl[c], r = stl[64 + c];
#pragma unroll
    for (int u = 0; u < 8; u++) xa[(t0 + u) * 72 + c] = f2bs((bs2f(v8[u]) - m) * r);
  }
  {
    int c = tid >> 2, j0 = (tid & 3) * 16;
    const float4* wr = (const float4*)(Wk + c * 64 + j0);
    float4 w0 = wr[0], w1 = wr[1], w2 = wr[2], w3 = wr[3];
    float wv[16] = {w0.x,w0.y,w0.z,w0.w, w1.x,w1.y,w1.z,w1.w,
                    w2.x,w2.y,w2.z,w2.w, w3.x,w3.y,w3.z,w3.w};
#pragma unroll
    for (int u = 0; u < 16; u++) wb[(j0 + u) * 72 + c] = f2bs(wv[u]);
  }
  __syncthreads();

  int wv_ = tid >> 6, lane = tid & 63, quad = lane >> 4, l15 = lane & 15;
  const short* arow = &xa[(wv_ * 16 + l15) * 72 + quad * 8];
  int orow0 = (wv_ * 16 + quad * 4);

  {
    short8 a0 = *(const short8*)(arow);
    short8 a1 = *(const short8*)(arow + 32);
#pragma unroll
    for (int nt = 0; nt < 4; nt++) {
      const short* brow = &wb[(nt * 16 + l15) * 72 + quad * 8];
      short8 b0 = *(const short8*)(brow);
      short8 b1 = *(const short8*)(brow + 32);
      f32x4 acc = {0.f, 0.f, 0.f, 0.f};
      acc = __builtin_amdgcn_mfma_f32_16x16x32_bf16(a0, b0, acc, 0, 0, 0);
      acc = __builtin_amdgcn_mfma_f32_16x16x32_bf16(a1, b1, acc, 0, 0, 0);
      float bval = bk[nt * 16 + l15];
#pragma unroll
      for (int r = 0; r < 4; r++)
        ob[(orow0 + r) * 72 + nt * 16 + l15] = f2bs(acc[r] + bval);
    }
  }
  __syncthreads();
  {
    int row = tid >> 2, col0 = (tid & 3) * 16;
    short8 o0 = *(const short8*)(&ob[row * 72 + col0]);
    short8 o1 = *(const short8*)(&ob[row * 72 + col0 + 8]);
    *(short8*)(kbuf + (size_t)(p0 + row) * 64 + col0) = o0;
    *(short8*)(kbuf + (size_t)(p0 + row) * 64 + col0 + 8) = o1;
    int c = tid >> 2, j0 = (tid & 3) * 16;
    const float4* wr = (const float4*)(Wv + c * 64 + j0);
    float4 w0 = wr[0], w1 = wr[1], w2 = wr[2], w3 = wr[3];
    float wvv[16] = {w0.x,w0.y,w0.z,w0.w, w1.x,w1.y,w1.z,w1.w,
                     w2.x,w2.y,w2.z,w2.w, w3.x,w3.y,w3.z,w3.w};
#pragma unroll
    for (int u = 0; u < 16; u++) wb[(j0 + u) * 72 + c] = f2bs(wvv[u]);
  }
  __syncthreads();
  {
    short8 a0 = *(const short8*)(arow);
    short8 a1 = *(const short8*)(arow + 32);
#pragma unroll
    for (int nt = 0; nt < 4; nt++) {
      const short* brow = &wb[(nt * 16 + l15) * 72 + quad * 8];
      short8 b0 = *(const short8*)(brow);
      short8 b1 = *(const short8*)(brow + 32);
      f32x4 acc = {0.f, 0.f, 0.f, 0.f};
      acc = __builtin_amdgcn_mfma_f32_16x16x32_bf16(a0, b0, acc, 0, 0, 0);
      acc = __builtin_amdgcn_mfma_f32_16x16x32_bf16(a1, b1, acc, 0, 0, 0);
      float bval = bv[nt * 16 + l15];
#pragma unroll
      for (int r = 0; r < 4; r++)
        ob[(orow0 + r) * 72 + nt * 16 + l15] = f2bs(acc[r] + bval);
    }
  }
  __syncthreads();
  {
    int row = tid >> 2, col0 = (tid & 3) * 16;
    short8 o0 = *(const short8*)(&ob[row * 72 + col0]);
    short8 o1 = *(const short8*)(&ob[row * 72 + col0 + 8]);
    *(short8*)(vbuf + (size_t)(p0 + row) * 64 + col0) = o0;
    *(short8*)(vbuf + (size_t)(p0 + row) * 64 + col0 + 8) = o1;
  }
  for (int ii = tid; ii < 1024; ii += 256) {
    int c = ii >> 4, t0 = (ii & 15) * 4;
    float4 v = *(const float4*)(skip + (size_t)c * NPOS + p0 + t0);
    float m = stl[128 + c], r = stl[192 + c];
    xa[(t0 + 0) * 72 + c] = f2bs((v.x - m) * r);
    xa[(t0 + 1) * 72 + c] = f2bs((v.y - m) * r);
    xa[(t0 + 2) * 72 + c] = f2bs((v.z - m) * r);
    xa[(t0 + 3) * 72 + c] = f2bs((v.w - m) * r);
  }
  {
    int c = tid >> 2, j0 = (tid & 3) * 16;
    const float4* wr = (const float4*)(Wq + c * 64 + j0);
    float4 w0 = wr[0], w1 = wr[1], w2 = wr[2], w3 = wr[3];
    float wq_[16] = {w0.x,w0.y,w0.z,w0.w, w1.x,w1.y,w1.z,w1.w,
                     w2.x,w2.y,w2.z,w2.w, w3.x,w3.y,w3.z,w3.w};
#pragma unroll
    for (int u = 0; u < 16; u++) wb[(j0 + u) * 72 + c] = f2bs(wq_[u]);
  }
  __syncthreads();
  {
    const float scale = 0.35355339059327373f;
    short8 a0 = *(const short8*)(arow);
    short8 a1 = *(const short8*)(arow + 32);
#pragma unroll
    for (int nt = 0; nt < 4; nt++) {
      const short* brow = &wb[(nt * 16 + l15) * 72 + quad * 8];
      short8 b0 = *(const short8*)(brow);
      short8 b1 = *(const short8*)(brow + 32);
      f32x4 acc = {0.f, 0.f, 0.f, 0.f};
      acc = __builtin_amdgcn_mfma_f32_16x16x32_bf16(a0, b0, acc, 0, 0, 0);
      acc = __builtin_amdgcn_mfma_f32_16x16x32_bf16(a1, b1, acc, 0, 0, 0);
      float bval = bq[nt * 16 + l15];
#pragma unroll
      for (int r = 0; r < 4; r++)
        ob[(orow0 + r) * 72 + nt * 16 + l15] = f2bs((acc[r] + bval) * scale);
    }
  }
  __syncthreads();
  {
    int row = tid >> 2, col0 = (tid & 3) * 16;
    short8 o0 = *(const short8*)(&ob[row * 72 + col0]);
    short8 o1 = *(const short8*)(&ob[row * 72 + col0 + 8]);
    *(short8*)(qbuf + (size_t)(p0 + row) * 64 + col0) = o0;
    *(short8*)(qbuf + (size_t)(p0 + row) * 64 + col0 + 8) = o1;
  }
}

// K3: 27-neighbor attention, 2 teams/wave (lane bit 3) x 14 neighbors each
// (team1 slot 0 is a softmax-neutral dummy), merged via shfl_xor(8).
// 256 threads = 16 pos x 2 teams x 8 heads; 4096 blocks; XCD swizzle.
__global__ __launch_bounds__(256, 5) void k_attn(
    const bf16* __restrict__ qbuf, const bf16* __restrict__ kbuf,
    const bf16* __restrict__ vbuf,
    const float* __restrict__ Wo, const float* __restrict__ bo,
    const float* __restrict__ rpb, float* __restrict__ out) {
  __shared__ float rp[1000];
  __shared__ float wo[4096];
  __shared__ float oT[16 * 65];
  int tid = threadIdx.x;
  int b = blockIdx.x;
  int sb = ((b & 7) << 9) + (b >> 3);  // XCD-contiguous spatial swizzle
  int p0 = sb * 16;                    // one (h,w) column, all 16 z
  for (int i = tid; i < 1000; i += 256) rp[i] = rpb[i];
  for (int i = tid; i < 1024; i += 256)
    ((float4*)wo)[i] = ((const float4*)Wo)[i];
  __syncthreads();

  int head = tid & 7, team = (tid >> 3) & 1, pp = tid >> 4;
  int p = p0 + pp;
  int h = p >> 10, w = (p >> 4) & 63, z = p & 15;

  short8 q8 = *(const short8*)(qbuf + (size_t)p * 64 + head * 8);
  float q[8];
#pragma unroll
  for (int d = 0; d < 8; d++) q[d] = bs2f(q8[d]);

  int sh = h - 1; if (sh < 0) sh = 0; if (sh > 61) sh = 61;
  int sw = w - 1; if (sw < 0) sw = 0; if (sw > 61) sw = 61;
  int sz = z - 1; if (sz < 0) sz = 0; if (sz > 13) sz = 13;

  const bf16* kb = kbuf + (size_t)(sh * 1024 + sw * 16 + sz) * 64 + head * 8;
  const bf16* vb = vbuf + (size_t)(sh * 1024 + sw * 16 + sz) * 64 + head * 8;
  int rbase = ((sh - h + 2) * 5 + (sw - w + 2)) * 5 + (sz - z + 2) + head * 125;

  // team0: j=0..13; team1: j=13..26 (slot 0 = j13 dummy, s forced -inf)
  static constexpr int CJ0[14] = {0, 64, 128, 1024, 1088, 1152, 2048, 2112,
                                  2176, 65536, 65600, 65664, 66560, 66624};
  static constexpr int CJ1[14] = {66624, 66688, 67584, 67648, 67712, 131072,
                                  131136, 131200, 132096, 132160, 132224,
                                  133120, 133184, 133248};
  static constexpr int RJ0[14] = {0, 1, 2, 5, 6, 7, 10, 11, 12, 25, 26, 27, 30, 31};
  static constexpr int RJ1[14] = {31, 32, 35, 36, 37, 50, 51, 52, 55, 56, 57,
                                  60, 61, 62};

  float s[14];
#pragma unroll
  for (int jj = 0; jj < 14; jj++) {
    int coff = team ? CJ1[jj] : CJ0[jj];
    int roff = team ? RJ1[jj] : RJ0[jj];
    short8 k8 = *(const short8*)(kb + coff);
    float sv = q[0] * bs2f(k8[0]) + q[1] * bs2f(k8[1]) +
               q[2] * bs2f(k8[2]) + q[3] * bs2f(k8[3]) +
               q[4] * bs2f(k8[4]) + q[5] * bs2f(k8[5]) +
               q[6] * bs2f(k8[6]) + q[7] * bs2f(k8[7]);
    s[jj] = sv + rp[rbase + roff];
  }
  if (team) s[0] = -1e30f;  // dummy slot

  float M = fmaxf(s[12], s[13]);
#pragma unroll
  for (int j = 0; j < 6; j++) M = fmaxf(M, fmaxf(s[2 * j], s[2 * j + 1]));
  M = fmaxf(M, __shfl_xor(M, 8, 64));  // cross-team max

  float lrun = 0.f;
  float oa[8];
#pragma unroll
  for (int d = 0; d < 8; d++) oa[d] = 0.f;
#pragma unroll
  for (int jj = 0; jj < 14; jj++) {
    int coff = team ? CJ1[jj] : CJ0[jj];
    short8 v8 = *(const short8*)(vb + coff);
    float pw = __expf(s[jj] - M);
    lrun += pw;
#pragma unroll
    for (int d = 0; d < 8; d++) oa[d] += pw * bs2f(v8[d]);
  }
  // cross-team merge
  lrun += __shfl_xor(lrun, 8, 64);
#pragma unroll
  for (int d = 0; d < 8; d++) oa[d] += __shfl_xor(oa[d], 8, 64);
  float inv = 1.0f / lrun;
  if (team == 0) {
#pragma unroll
    for (int d = 0; d < 8; d++) oT[pp * 65 + head * 8 + d] = oa[d] * inv;
  }
  __syncthreads();

  // output projection: thread -> (pos = tid&15, channels chg*4..chg*4+3)
  int pos = tid & 15, chg = tid >> 4, ch0 = chg * 4;
  float4 bo4 = *(const float4*)(bo + ch0);
  float a0 = bo4.x, a1 = bo4.y, a2 = bo4.z, a3 = bo4.w;
  for (int j = 0; j < 64; j++) {
    float ov = oT[pos * 65 + j];
    float4 wv = *(const float4*)(&wo[j * 64 + ch0]);
    a0 += ov * wv.x; a1 += ov * wv.y; a2 += ov * wv.z; a3 += ov * wv.w;
  }
  out[(size_t)(ch0 + 0) * NPOS + p0 + pos] = a0;
  out[(size_t)(ch0 + 1) * NPOS + p0 + pos] = a1;
  out[(size_t)(ch0 + 2) * NPOS + p0 + pos] = a2;
  out[(size_t)(ch0 + 3) * NPOS + p0 + pos] = a3;
}

extern "C" void kernel_launch(void* const* d_in, const int* in_sizes, int n_in,
                              void* d_out, int out_size, void* d_ws, size_t ws_size,
                              hipStream_t stream) {
  const float* x    = (const float*)d_in[0];
  const float* skip = (const float*)d_in[1];
  const float* Wq   = (const float*)d_in[2];
  const float* bq   = (const float*)d_in[3];
  const float* Wk   = (const float*)d_in[4];
  const float* bk   = (const float*)d_in[5];
  const float* Wv   = (const float*)d_in[6];
  const float* bv   = (const float*)d_in[7];
  const float* Wo   = (const float*)d_in[8];
  const float* bo   = (const float*)d_in[9];
  const float* rpb  = (const float*)d_in[10];

  bf16* xu        = (bf16*)d_ws;                                 // 8 MB
  bf16* kbuf      = (bf16*)((char*)d_ws + ((size_t)8 << 20));    // 8 MB
  bf16* vbuf      = (bf16*)((char*)d_ws + ((size_t)16 << 20));   // 8 MB
  bf16* qbuf      = (bf16*)((char*)d_ws + ((size_t)24 << 20));   // 8 MB
  float* partials = (float*)((char*)d_ws + ((size_t)32 << 20));  // 4096 fp32
  float* out = (float*)d_out;

  hipLaunchKernelGGL(k_partial, dim3(2048), dim3(256), 0, stream, x, skip, xu,
                     partials);
  hipLaunchKernelGGL(k_proj_mfma, dim3(1024), dim3(256), 0, stream, xu, skip,
                     partials, Wk, bk, Wv, bv, Wq, bq, kbuf, vbuf, qbuf);
  hipLaunchKernelGGL(k_attn, dim3(4096), dim3(256), 0, stream, qbuf, kbuf, vbuf,
                     Wo, bo, rpb, out);
}

// Round 13
// 145.974 us; speedup vs baseline: 1.4063x; 1.4063x over previous
//
#include <hip/hip_runtime.h>
#include <hip/hip_bf16.h>

typedef __hip_bfloat16 bf16;
typedef __attribute__((ext_vector_type(8))) short short8;
typedef __attribute__((ext_vector_type(4))) float f32x4;

static constexpr int NPOS = 65536;  // 64*64*16

__device__ __forceinline__ float bs2f(short s) {
  union { float f; unsigned u; } cv;
  cv.u = ((unsigned)(unsigned short)s) << 16;
  return cv.f;
}
__device__ __forceinline__ short f2bs(float f) {
  bf16 b = __float2bfloat16(f);
  short r;
  __builtin_memcpy(&r, &b, 2);
  return r;
}

// K1a: partial sums + xu materialization (bf16). 2048 blocks. (unchanged)
__global__ __launch_bounds__(256) void k_partial(const float* __restrict__ x,
                                                 const float* __restrict__ skip,
                                                 bf16* __restrict__ xu,
                                                 float* __restrict__ partials) {
  __shared__ float s1[256];
  __shared__ float s2[256];
  int b = blockIdx.x, tid = threadIdx.x;
  float sum = 0.f, sq = 0.f;
  if (b < 1024) {
    int c = b >> 4;
    int h = (b & 15) * 4 + (tid >> 6);
    int w = tid & 63;
    float fh = (float)h * (31.0f / 63.0f);
    int ih = (int)fh; if (ih > 30) ih = 30;
    float wh = fh - (float)ih;
    float fw = (float)w * (31.0f / 63.0f);
    int iw = (int)fw; if (iw > 30) iw = 30;
    float ww = fw - (float)iw;
    const float* base = x + c * 8192 + ih * 256 + iw * 8;
    float4 A0 = *(const float4*)(base);
    float4 A1 = *(const float4*)(base + 4);
    float4 B0 = *(const float4*)(base + 8);
    float4 B1 = *(const float4*)(base + 12);
    float4 C0 = *(const float4*)(base + 256);
    float4 C1 = *(const float4*)(base + 260);
    float4 D0 = *(const float4*)(base + 264);
    float4 D1 = *(const float4*)(base + 268);
    float ra[8] = {A0.x, A0.y, A0.z, A0.w, A1.x, A1.y, A1.z, A1.w};
    float rb[8] = {B0.x, B0.y, B0.z, B0.w, B1.x, B1.y, B1.z, B1.w};
    float rc[8] = {C0.x, C0.y, C0.z, C0.w, C1.x, C1.y, C1.z, C1.w};
    float rd[8] = {D0.x, D0.y, D0.z, D0.w, D1.x, D1.y, D1.z, D1.w};
    short8 o0, o1;
#define ZSTEP(zz)                                                              \
  {                                                                            \
    constexpr float fz = (float)(zz) * (7.0f / 15.0f);                         \
    constexpr int izr = (int)fz;                                               \
    constexpr int iz = (izr > 6) ? 6 : izr;                                    \
    constexpr float wz = fz - (float)iz;                                       \
    float va = ra[iz] * (1.f - wz) + ra[iz + 1] * wz;                          \
    float vb = rb[iz] * (1.f - wz) + rb[iz + 1] * wz;                          \
    float vc = rc[iz] * (1.f - wz) + rc[iz + 1] * wz;                          \
    float vd = rd[iz] * (1.f - wz) + rd[iz + 1] * wz;                          \
    float v0 = va * (1.f - ww) + vb * ww;                                      \
    float v1 = vc * (1.f - ww) + vd * ww;                                      \
    float v = v0 * (1.f - wh) + v1 * wh;                                       \
    sum += v; sq += v * v;                                                     \
    if ((zz) < 8) o0[(zz) & 7] = f2bs(v); else o1[(zz) & 7] = f2bs(v);         \
  }
    ZSTEP(0) ZSTEP(1) ZSTEP(2) ZSTEP(3) ZSTEP(4) ZSTEP(5) ZSTEP(6) ZSTEP(7)
    ZSTEP(8) ZSTEP(9) ZSTEP(10) ZSTEP(11) ZSTEP(12) ZSTEP(13) ZSTEP(14) ZSTEP(15)
#undef ZSTEP
    bf16* xo = xu + (size_t)c * NPOS + h * 1024 + w * 16;
    *(short8*)xo = o0;
    *(short8*)(xo + 8) = o1;
  } else {
    int bb = b - 1024;
    const float4* p =
        (const float4*)(skip + (size_t)(bb >> 4) * NPOS + (bb & 15) * 4096);
    for (int i = tid; i < 1024; i += 256) {
      float4 v = p[i];
      sum += v.x + v.y + v.z + v.w;
      sq += v.x * v.x + v.y * v.y + v.z * v.z + v.w * v.w;
    }
  }
  s1[tid] = sum; s2[tid] = sq;
  __syncthreads();
  for (int s = 128; s > 0; s >>= 1) {
    if (tid < s) { s1[tid] += s1[tid + s]; s2[tid] += s2[tid + s]; }
    __syncthreads();
  }
  if (tid == 0) { partials[2 * b] = s1[0]; partials[2 * b + 1] = s2[0]; }
}

// K2: MFMA projection (unchanged from R11).
__global__ __launch_bounds__(256) void k_proj_mfma(
    const bf16* __restrict__ xu, const float* __restrict__ skip,
    const float* __restrict__ partials,
    const float* __restrict__ Wk, const float* __restrict__ bk,
    const float* __restrict__ Wv, const float* __restrict__ bv,
    const float* __restrict__ Wq, const float* __restrict__ bq,
    bf16* __restrict__ kbuf, bf16* __restrict__ vbuf, bf16* __restrict__ qbuf) {
  __shared__ float stl[256];
  __shared__ short xa[64 * 72];
  __shared__ short wb[64 * 72];
  __shared__ short ob[64 * 72];
  int tid = threadIdx.x;
  int p0 = blockIdx.x * 64;

  if (tid < 128) {
    int isk = tid >> 6, c = tid & 63;
    int base = isk ? (1024 + c * 16) : (c * 16);
    float sum = 0.f, sq = 0.f;
#pragma unroll
    for (int j = 0; j < 16; j++) {
      sum += partials[2 * (base + j)];
      sq  += partials[2 * (base + j) + 1];
    }
    float m = sum * (1.0f / NPOS);
    float var = sq * (1.0f / NPOS) - m * m;
    stl[isk * 128 + c] = m;
    stl[isk * 128 + 64 + c] = rsqrtf(var + 1e-5f);
  }
  __syncthreads();

  for (int ii = tid; ii < 512; ii += 256) {
    int c = ii >> 3, t0 = (ii & 7) * 8;
    short8 v8 = *(const short8*)(xu + (size_t)c * NPOS + p0 + t0);
    float m = stl[c], r = stl[64 + c];
#pragma unroll
    for (int u = 0; u < 8; u++) xa[(t0 + u) * 72 + c] = f2bs((bs2f(v8[u]) - m) * r);
  }
  {
    int c = tid >> 2, j0 = (tid & 3) * 16;
    const float4* wr = (const float4*)(Wk + c * 64 + j0);
    float4 w0 = wr[0], w1 = wr[1], w2 = wr[2], w3 = wr[3];
    float wv[16] = {w0.x,w0.y,w0.z,w0.w, w1.x,w1.y,w1.z,w1.w,
                    w2.x,w2.y,w2.z,w2.w, w3.x,w3.y,w3.z,w3.w};
#pragma unroll
    for (int u = 0; u < 16; u++) wb[(j0 + u) * 72 + c] = f2bs(wv[u]);
  }
  __syncthreads();

  int wv_ = tid >> 6, lane = tid & 63, quad = lane >> 4, l15 = lane & 15;
  const short* arow = &xa[(wv_ * 16 + l15) * 72 + quad * 8];
  int orow0 = (wv_ * 16 + quad * 4);

  {
    short8 a0 = *(const short8*)(arow);
    short8 a1 = *(const short8*)(arow + 32);
#pragma unroll
    for (int nt = 0; nt < 4; nt++) {
      const short* brow = &wb[(nt * 16 + l15) * 72 + quad * 8];
      short8 b0 = *(const short8*)(brow);
      short8 b1 = *(const short8*)(brow + 32);
      f32x4 acc = {0.f, 0.f, 0.f, 0.f};
      acc = __builtin_amdgcn_mfma_f32_16x16x32_bf16(a0, b0, acc, 0, 0, 0);
      acc = __builtin_amdgcn_mfma_f32_16x16x32_bf16(a1, b1, acc, 0, 0, 0);
      float bval = bk[nt * 16 + l15];
#pragma unroll
      for (int r = 0; r < 4; r++)
        ob[(orow0 + r) * 72 + nt * 16 + l15] = f2bs(acc[r] + bval);
    }
  }
  __syncthreads();
  {
    int row = tid >> 2, col0 = (tid & 3) * 16;
    short8 o0 = *(const short8*)(&ob[row * 72 + col0]);
    short8 o1 = *(const short8*)(&ob[row * 72 + col0 + 8]);
    *(short8*)(kbuf + (size_t)(p0 + row) * 64 + col0) = o0;
    *(short8*)(kbuf + (size_t)(p0 + row) * 64 + col0 + 8) = o1;
    int c = tid >> 2, j0 = (tid & 3) * 16;
    const float4* wr = (const float4*)(Wv + c * 64 + j0);
    float4 w0 = wr[0], w1 = wr[1], w2 = wr[2], w3 = wr[3];
    float wvv[16] = {w0.x,w0.y,w0.z,w0.w, w1.x,w1.y,w1.z,w1.w,
                     w2.x,w2.y,w2.z,w2.w, w3.x,w3.y,w3.z,w3.w};
#pragma unroll
    for (int u = 0; u < 16; u++) wb[(j0 + u) * 72 + c] = f2bs(wvv[u]);
  }
  __syncthreads();
  {
    short8 a0 = *(const short8*)(arow);
    short8 a1 = *(const short8*)(arow + 32);
#pragma unroll
    for (int nt = 0; nt < 4; nt++) {
      const short* brow = &wb[(nt * 16 + l15) * 72 + quad * 8];
      short8 b0 = *(const short8*)(brow);
      short8 b1 = *(const short8*)(brow + 32);
      f32x4 acc = {0.f, 0.f, 0.f, 0.f};
      acc = __builtin_amdgcn_mfma_f32_16x16x32_bf16(a0, b0, acc, 0, 0, 0);
      acc = __builtin_amdgcn_mfma_f32_16x16x32_bf16(a1, b1, acc, 0, 0, 0);
      float bval = bv[nt * 16 + l15];
#pragma unroll
      for (int r = 0; r < 4; r++)
        ob[(orow0 + r) * 72 + nt * 16 + l15] = f2bs(acc[r] + bval);
    }
  }
  __syncthreads();
  {
    int row = tid >> 2, col0 = (tid & 3) * 16;
    short8 o0 = *(const short8*)(&ob[row * 72 + col0]);
    short8 o1 = *(const short8*)(&ob[row * 72 + col0 + 8]);
    *(short8*)(vbuf + (size_t)(p0 + row) * 64 + col0) = o0;
    *(short8*)(vbuf + (size_t)(p0 + row) * 64 + col0 + 8) = o1;
  }
  for (int ii = tid; ii < 1024; ii += 256) {
    int c = ii >> 4, t0 = (ii & 15) * 4;
    float4 v = *(const float4*)(skip + (size_t)c * NPOS + p0 + t0);
    float m = stl[128 + c], r = stl[192 + c];
    xa[(t0 + 0) * 72 + c] = f2bs((v.x - m) * r);
    xa[(t0 + 1) * 72 + c] = f2bs((v.y - m) * r);
    xa[(t0 + 2) * 72 + c] = f2bs((v.z - m) * r);
    xa[(t0 + 3) * 72 + c] = f2bs((v.w - m) * r);
  }
  {
    int c = tid >> 2, j0 = (tid & 3) * 16;
    const float4* wr = (const float4*)(Wq + c * 64 + j0);
    float4 w0 = wr[0], w1 = wr[1], w2 = wr[2], w3 = wr[3];
    float wq_[16] = {w0.x,w0.y,w0.z,w0.w, w1.x,w1.y,w1.z,w1.w,
                     w2.x,w2.y,w2.z,w2.w, w3.x,w3.y,w3.z,w3.w};
#pragma unroll
    for (int u = 0; u < 16; u++) wb[(j0 + u) * 72 + c] = f2bs(wq_[u]);
  }
  __syncthreads();
  {
    const float scale = 0.35355339059327373f;
    short8 a0 = *(const short8*)(arow);
    short8 a1 = *(const short8*)(arow + 32);
#pragma unroll
    for (int nt = 0; nt < 4; nt++) {
      const short* brow = &wb[(nt * 16 + l15) * 72 + quad * 8];
      short8 b0 = *(const short8*)(brow);
      short8 b1 = *(const short8*)(brow + 32);
      f32x4 acc = {0.f, 0.f, 0.f, 0.f};
      acc = __builtin_amdgcn_mfma_f32_16x16x32_bf16(a0, b0, acc, 0, 0, 0);
      acc = __builtin_amdgcn_mfma_f32_16x16x32_bf16(a1, b1, acc, 0, 0, 0);
      float bval = bq[nt * 16 + l15];
#pragma unroll
      for (int r = 0; r < 4; r++)
        ob[(orow0 + r) * 72 + nt * 16 + l15] = f2bs((acc[r] + bval) * scale);
    }
  }
  __syncthreads();
  {
    int row = tid >> 2, col0 = (tid & 3) * 16;
    short8 o0 = *(const short8*)(&ob[row * 72 + col0]);
    short8 o1 = *(const short8*)(&ob[row * 72 + col0 + 8]);
    *(short8*)(qbuf + (size_t)(p0 + row) * 64 + col0) = o0;
    *(short8*)(qbuf + (size_t)(p0 + row) * 64 + col0 + 8) = o1;
  }
}

// K3: 27-neighbor attention, 2 teams/wave x 14 neighbors, shfl_xor(8) merge.
// 256 threads = 16 pos x 2 teams x 8 heads; 4096 blocks; XCD swizzle.
// __launch_bounds__(256,2): VGPR cap = 65536/(64*8) = 128 — fits
// s[14]+q[8]+oa[8] (R12's (256,5) capped at 48 and spilled 280 MB).
__global__ __launch_bounds__(256, 2) void k_attn(
    const bf16* __restrict__ qbuf, const bf16* __restrict__ kbuf,
    const bf16* __restrict__ vbuf,
    const float* __restrict__ Wo, const float* __restrict__ bo,
    const float* __restrict__ rpb, float* __restrict__ out) {
  __shared__ float rp[1000];
  __shared__ float wo[4096];
  __shared__ float oT[16 * 65];
  int tid = threadIdx.x;
  int b = blockIdx.x;
  int sb = ((b & 7) << 9) + (b >> 3);  // XCD-contiguous spatial swizzle
  int p0 = sb * 16;                    // one (h,w) column, all 16 z
  for (int i = tid; i < 1000; i += 256) rp[i] = rpb[i];
  for (int i = tid; i < 1024; i += 256)
    ((float4*)wo)[i] = ((const float4*)Wo)[i];
  __syncthreads();

  int head = tid & 7, team = (tid >> 3) & 1, pp = tid >> 4;
  int p = p0 + pp;
  int h = p >> 10, w = (p >> 4) & 63, z = p & 15;

  short8 q8 = *(const short8*)(qbuf + (size_t)p * 64 + head * 8);
  float q[8];
#pragma unroll
  for (int d = 0; d < 8; d++) q[d] = bs2f(q8[d]);

  int sh = h - 1; if (sh < 0) sh = 0; if (sh > 61) sh = 61;
  int sw = w - 1; if (sw < 0) sw = 0; if (sw > 61) sw = 61;
  int sz = z - 1; if (sz < 0) sz = 0; if (sz > 13) sz = 13;

  const bf16* kb = kbuf + (size_t)(sh * 1024 + sw * 16 + sz) * 64 + head * 8;
  const bf16* vb = vbuf + (size_t)(sh * 1024 + sw * 16 + sz) * 64 + head * 8;
  int rbase = ((sh - h + 2) * 5 + (sw - w + 2)) * 5 + (sz - z + 2) + head * 125;

  // team0: j=0..13; team1: j=13..26 (slot 0 = j13 dummy, s forced -inf)
  static constexpr int CJ0[14] = {0, 64, 128, 1024, 1088, 1152, 2048, 2112,
                                  2176, 65536, 65600, 65664, 66560, 66624};
  static constexpr int CJ1[14] = {66624, 66688, 67584, 67648, 67712, 131072,
                                  131136, 131200, 132096, 132160, 132224,
                                  133120, 133184, 133248};
  static constexpr int RJ0[14] = {0, 1, 2, 5, 6, 7, 10, 11, 12, 25, 26, 27, 30, 31};
  static constexpr int RJ1[14] = {31, 32, 35, 36, 37, 50, 51, 52, 55, 56, 57,
                                  60, 61, 62};

  float s[14];
#pragma unroll
  for (int jj = 0; jj < 14; jj++) {
    int coff = team ? CJ1[jj] : CJ0[jj];
    int roff = team ? RJ1[jj] : RJ0[jj];
    short8 k8 = *(const short8*)(kb + coff);
    float sv = q[0] * bs2f(k8[0]) + q[1] * bs2f(k8[1]) +
               q[2] * bs2f(k8[2]) + q[3] * bs2f(k8[3]) +
               q[4] * bs2f(k8[4]) + q[5] * bs2f(k8[5]) +
               q[6] * bs2f(k8[6]) + q[7] * bs2f(k8[7]);
    s[jj] = sv + rp[rbase + roff];
  }
  if (team) s[0] = -1e30f;  // dummy slot

  float M = fmaxf(s[12], s[13]);
#pragma unroll
  for (int j = 0; j < 6; j++) M = fmaxf(M, fmaxf(s[2 * j], s[2 * j + 1]));
  M = fmaxf(M, __shfl_xor(M, 8, 64));  // cross-team max

  float lrun = 0.f;
  float oa[8];
#pragma unroll
  for (int d = 0; d < 8; d++) oa[d] = 0.f;
#pragma unroll
  for (int jj = 0; jj < 14; jj++) {
    int coff = team ? CJ1[jj] : CJ0[jj];
    short8 v8 = *(const short8*)(vb + coff);
    float pw = __expf(s[jj] - M);
    lrun += pw;
#pragma unroll
    for (int d = 0; d < 8; d++) oa[d] += pw * bs2f(v8[d]);
  }
  // cross-team merge
  lrun += __shfl_xor(lrun, 8, 64);
#pragma unroll
  for (int d = 0; d < 8; d++) oa[d] += __shfl_xor(oa[d], 8, 64);
  float inv = 1.0f / lrun;
  if (team == 0) {
#pragma unroll
    for (int d = 0; d < 8; d++) oT[pp * 65 + head * 8 + d] = oa[d] * inv;
  }
  __syncthreads();

  // output projection: thread -> (pos = tid&15, channels chg*4..chg*4+3)
  int pos = tid & 15, chg = tid >> 4, ch0 = chg * 4;
  float4 bo4 = *(const float4*)(bo + ch0);
  float a0 = bo4.x, a1 = bo4.y, a2 = bo4.z, a3 = bo4.w;
  for (int j = 0; j < 64; j++) {
    float ov = oT[pos * 65 + j];
    float4 wv = *(const float4*)(&wo[j * 64 + ch0]);
    a0 += ov * wv.x; a1 += ov * wv.y; a2 += ov * wv.z; a3 += ov * wv.w;
  }
  out[(size_t)(ch0 + 0) * NPOS + p0 + pos] = a0;
  out[(size_t)(ch0 + 1) * NPOS + p0 + pos] = a1;
  out[(size_t)(ch0 + 2) * NPOS + p0 + pos] = a2;
  out[(size_t)(ch0 + 3) * NPOS + p0 + pos] = a3;
}

extern "C" void kernel_launch(void* const* d_in, const int* in_sizes, int n_in,
                              void* d_out, int out_size, void* d_ws, size_t ws_size,
                              hipStream_t stream) {
  const float* x    = (const float*)d_in[0];
  const float* skip = (const float*)d_in[1];
  const float* Wq   = (const float*)d_in[2];
  const float* bq   = (const float*)d_in[3];
  const float* Wk   = (const float*)d_in[4];
  const float* bk   = (const float*)d_in[5];
  const float* Wv   = (const float*)d_in[6];
  const float* bv   = (const float*)d_in[7];
  const float* Wo   = (const float*)d_in[8];
  const float* bo   = (const float*)d_in[9];
  const float* rpb  = (const float*)d_in[10];

  bf16* xu        = (bf16*)d_ws;                                 // 8 MB
  bf16* kbuf      = (bf16*)((char*)d_ws + ((size_t)8 << 20));    // 8 MB
  bf16* vbuf      = (bf16*)((char*)d_ws + ((size_t)16 << 20));   // 8 MB
  bf16* qbuf      = (bf16*)((char*)d_ws + ((size_t)24 << 20));   // 8 MB
  float* partials = (float*)((char*)d_ws + ((size_t)32 << 20));  // 4096 fp32
  float* out = (float*)d_out;

  hipLaunchKernelGGL(k_partial, dim3(2048), dim3(256), 0, stream, x, skip, xu,
                     partials);
  hipLaunchKernelGGL(k_proj_mfma, dim3(1024), dim3(256), 0, stream, xu, skip,
                     partials, Wk, bk, Wv, bv, Wq, bq, kbuf, vbuf, qbuf);
  hipLaunchKernelGGL(k_attn, dim3(4096), dim3(256), 0, stream, qbuf, kbuf, vbuf,
                     Wo, bo, rpb, out);
}